// Round 17
// baseline (236.250 us; speedup 1.0000x reference)
//
#include <hip/hip_runtime.h>
#include <cmath>

// ---------------------------------------------------------------------------
// CrossAttention: B=4, N=1024, C=1024, H=16, HD=64
//   q = x@Wq ; kv = k_in@Wkv ; p = softmax(q k^T /8); z = p*a; w = softmax(z)
//   out = (w@v)@Wproj + b
// Numerics (r5/r9-proven): plain bf16 GEMMs; 2nd softmax linear at budget:
//   out = (SumV + linv*W1) / (1024 + linv*e1), c = exp(s/8), linv = 1/sum c.
// v17: attn rewritten BARRIER-FREE — each wave owns one 16-q tile; the
// p-transpose goes through wave-private LDS (same-wave ds ordering, no
// __syncthreads anywhere); a is multiplied AFTER the transpose in the
// PV-A-frag domain (contiguous 16B loads from linear ab). 32x loop over
// 32-m chunks. L via l15-shfl reduce, e1 via l4-shfl reduce + bpermute.
// Rest (preps, merged q+kv GEMM, sumv, proj) = round-12 verbatim.
// ---------------------------------------------------------------------------

#define Bb 4
#define Nn 1024
#define Cc 1024
#define Hh 16
#define HD 64

typedef unsigned short u16;
typedef short bf16x8 __attribute__((ext_vector_type(8)));
typedef float f32x4 __attribute__((ext_vector_type(4)));
typedef unsigned short u16x4 __attribute__((ext_vector_type(4)));
typedef unsigned short u16x8 __attribute__((ext_vector_type(8)));
typedef __attribute__((address_space(1))) const void* gptr_t;
typedef __attribute__((address_space(3))) void* lptr_t;

__device__ __forceinline__ u16 f2b(float f) {
  union { float f; unsigned u; } x; x.f = f;
  unsigned u = x.u;
  return (u16)((u + 0x7FFFu + ((u >> 16) & 1u)) >> 16);
}
__device__ __forceinline__ float b2f(u16 h) {
  union { unsigned u; float f; } x; x.u = ((unsigned)h) << 16;
  return x.f;
}

// ---------------- prep: bf16 casts of x, k_in, attn_add (r12 verbatim) ------
__global__ __launch_bounds__(256) void prep_big(
    const float* __restrict__ x, const float* __restrict__ kin,
    const float* __restrict__ af,
    u16* __restrict__ xh, u16* __restrict__ kinh, u16* __restrict__ ab) {
  const int i = (blockIdx.x * 256 + threadIdx.x) * 8;   // 4M elems, grid 2048
  f32x4 x0 = *(const f32x4*)(x + i),   x1 = *(const f32x4*)(x + i + 4);
  f32x4 k0 = *(const f32x4*)(kin + i), k1 = *(const f32x4*)(kin + i + 4);
  f32x4 a0 = *(const f32x4*)(af + i),  a1 = *(const f32x4*)(af + i + 4);
  u16x8 xo, ko, ao;
  #pragma unroll
  for (int j = 0; j < 4; ++j) {
    xo[j] = f2b(x0[j]); xo[j + 4] = f2b(x1[j]);
    ko[j] = f2b(k0[j]); ko[j + 4] = f2b(k1[j]);
    ao[j] = f2b(a0[j]); ao[j + 4] = f2b(a1[j]);
  }
  *(u16x8*)(xh + i) = xo;
  *(u16x8*)(kinh + i) = ko;
  *(u16x8*)(ab + i) = ao;
}

// ---------------- tiled weight transposes (r12 verbatim) --------------------
__global__ __launch_bounds__(256) void prep_wt(
    const float* __restrict__ Wq, const float* __restrict__ Wkv,
    const float* __restrict__ Wp,
    u16* __restrict__ WqT, u16* __restrict__ WkvTh, u16* __restrict__ WpTh) {
  __shared__ float tile[64][65];
  int id = blockIdx.x;
  const float* src; int srcld; u16* dh; int ot0, it0;
  if (id < 256)      { src = Wq;  srcld = 1024; dh = WqT;
                       ot0 = (id >> 4) * 64; it0 = (id & 15) * 64; }
  else if (id < 768) { id -= 256; src = Wkv; srcld = 2048; dh = WkvTh;
                       ot0 = (id >> 4) * 64; it0 = (id & 15) * 64; }
  else               { id -= 768; src = Wp;  srcld = 1024; dh = WpTh;
                       ot0 = (id >> 4) * 64; it0 = (id & 15) * 64; }
  const int tr = threadIdx.x >> 4;
  const int tc = (threadIdx.x & 15) * 4;
  #pragma unroll
  for (int rr = 0; rr < 4; ++rr) {
    const int r = rr * 16 + tr;
    f32x4 v = *(const f32x4*)&src[(size_t)(it0 + r) * srcld + ot0 + tc];
    tile[r][tc] = v[0]; tile[r][tc + 1] = v[1];
    tile[r][tc + 2] = v[2]; tile[r][tc + 3] = v[3];
  }
  __syncthreads();
  #pragma unroll
  for (int rr = 0; rr < 4; ++rr) {
    const int o = rr * 16 + tr;
    u16x4 hv;
    #pragma unroll
    for (int j = 0; j < 4; ++j) hv[j] = f2b(tile[tc + j][o]);
    *(u16x4*)(dh + (size_t)(ot0 + o) * 1024 + it0 + tc) = hv;
  }
}

// ------- merged q+kv GEMM, 64x128 tile, one dispatch (r12 verbatim) ---------
__global__ __launch_bounds__(256) void gemm_qkv(
    const u16* __restrict__ xh, const u16* __restrict__ kinh,
    const u16* __restrict__ WqT, const u16* __restrict__ WkvTh,
    u16* __restrict__ qb, u16* __restrict__ kb, u16* __restrict__ vtb,
    float* __restrict__ vtf) {
  constexpr int K = 1024;
  __shared__ u16 As[64 * 32];
  __shared__ u16 Bs[128 * 32];
  const int tid = threadIdx.x;
  const int wave = tid >> 6, lane = tid & 63;
  const int l15 = lane & 15, l4 = lane >> 4;
  const int y = blockIdx.y;
  const bool isq = (y < 8);
  const u16* A  = isq ? xh : kinh;
  const u16* Bt = isq ? WqT : WkvTh;
  const int m0 = blockIdx.x * 64;
  const int n0 = (isq ? y : (y - 8)) * 128;
  const int wr = wave >> 1, wc = wave & 1;
  const int srow = tid >> 2, scol = (tid & 3) * 8;
  f32x4 acc[2][4] = {};
  const u16* gA  = A  + (size_t)(m0 + srow) * K + scol;
  const u16* gB0 = Bt + (size_t)(n0 + srow) * K + scol;
  const u16* gB1 = Bt + (size_t)(n0 + 64 + srow) * K + scol;
  for (int kt = 0; kt < K; kt += 32) {
    __syncthreads();
    __builtin_amdgcn_global_load_lds((gptr_t)(gA  + kt), (lptr_t)(As + wave * 512), 16, 0, 0);
    __builtin_amdgcn_global_load_lds((gptr_t)(gB0 + kt), (lptr_t)(Bs + wave * 512), 16, 0, 0);
    __builtin_amdgcn_global_load_lds((gptr_t)(gB1 + kt), (lptr_t)(Bs + 2048 + wave * 512), 16, 0, 0);
    __syncthreads();
    bf16x8 af[2], bf_[4];
    #pragma unroll
    for (int i = 0; i < 2; ++i)
      af[i] = *(const bf16x8*)(As + (wr * 32 + i * 16 + l15) * 32 + l4 * 8);
    #pragma unroll
    for (int i = 0; i < 4; ++i)
      bf_[i] = *(const bf16x8*)(Bs + (wc * 64 + i * 16 + l15) * 32 + l4 * 8);
    #pragma unroll
    for (int mi = 0; mi < 2; ++mi)
      #pragma unroll
      for (int ni = 0; ni < 4; ++ni)
        acc[mi][ni] = __builtin_amdgcn_mfma_f32_16x16x32_bf16(af[mi], bf_[ni], acc[mi][ni], 0, 0, 0);
  }
  #pragma unroll
  for (int mi = 0; mi < 2; ++mi)
    #pragma unroll
    for (int ni = 0; ni < 4; ++ni)
      #pragma unroll
      for (int r = 0; r < 4; ++r) {
        const int grow = m0 + wr * 32 + mi * 16 + l4 * 4 + r;   // b*N+n
        const int gcol = n0 + wc * 64 + ni * 16 + l15;
        const int bb = grow >> 10, n = grow & 1023;
        const float v = acc[mi][ni][r];
        if (isq) {
          const int hh = gcol >> 6, d = gcol & 63;
          qb[(((size_t)(bb * Hh + hh)) * Nn + n) * HD + d] = f2b(v);
        } else if (gcol < 1024) {   // k columns (block-uniform)
          const int hh = gcol >> 6, d = gcol & 63;
          kb[(((size_t)(bb * Hh + hh)) * Nn + n) * HD + d] = f2b(v);
        } else {                    // v columns
          const int cv = gcol - 1024;
          const int hh = cv >> 6, d = cv & 63;
          const size_t o = (((size_t)(bb * Hh + hh)) * HD + d) * Nn + n;
          vtf[o] = v;
          vtb[o] = f2b(v);
        }
      }
}

// ---------------- SumV[b][h][d] = sum_m v[m][d] (r12 verbatim) --------------
__global__ __launch_bounds__(256) void sumv_kernel(const float* __restrict__ vtf,
                                                   float* __restrict__ sv) {
  const int bh = blockIdx.x >> 2, d16 = blockIdx.x & 3;
  const int t = threadIdx.x;
  const int d = d16 * 16 + (t >> 4), part = t & 15;
  const float* src = vtf + ((size_t)bh * HD + d) * Nn + part * 64;
  float s = 0.f;
  #pragma unroll
  for (int i = 0; i < 64; i += 4) {
    f32x4 v = *(const f32x4*)(src + i);
    s += v[0] + v[1] + v[2] + v[3];
  }
  s += __shfl_xor(s, 1, 64);
  s += __shfl_xor(s, 2, 64);
  s += __shfl_xor(s, 4, 64);
  s += __shfl_xor(s, 8, 64);
  if (part == 0) sv[(size_t)bh * HD + d] = s;
}

// ---------------- fused double-softmax attention (v17: barrier-free) --------
// 4 independent wave-units/block; wave owns 16 q-rows of one (b,h).
// Per 32-m chunk: {4 QK MFMA -> c=exp2(s*C1) -> wave-private LDS (16x40,
// 16B-aligned rows); 1 b128 transpose-read; a-frag (16B, linear ab) mult;
// e1 accum; cvt_pk -> PV A-frag; 4 PV MFMA}. NO __syncthreads anywhere.
__global__ __launch_bounds__(256, 3) void attn_kernel(
    const u16* __restrict__ qb, const u16* __restrict__ kb,
    const u16* __restrict__ vtb, const float* __restrict__ sv,
    const u16* __restrict__ ab, u16* __restrict__ aoh) {
  __shared__ u16 ct[4][16 * 40];            // per-wave c tile, 80B rows (5KB)

  const int tid = threadIdx.x;
  const int wave = tid >> 6, lane = tid & 63;
  const int l15 = lane & 15, l4 = lane >> 4;
  const int bid = (blockIdx.x & 7) * 128 + (blockIdx.x >> 3);   // XCD chunking
  const int unit = bid * 4 + wave;          // 4096 wave-units
  const int qt = unit & 63, h = (unit >> 6) & 15, b = unit >> 10;
  const size_t bh = (size_t)(b * Hh + h);
  const u16* qg = qb + (bh * Nn + qt * 16) * HD;
  const u16* kl = kb + bh * Nn * HD + (size_t)l15 * HD + l4 * 8;
  const u16* vl = vtb + bh * HD * Nn + (size_t)l15 * Nn + l4 * 8;
  const u16* ag = ab + ((size_t)(b * Nn + qt * 16 + l15)) * Nn + l4 * 8;
  u16* cw = ct[wave];
  constexpr float C1 = 0.125f * 1.44269504f;    // (1/8)*log2(e)

  // q fragments (16 q-rows, K=64)
  bf16x8 qf0 = *(const bf16x8*)(qg + l15 * HD + l4 * 8);
  bf16x8 qf1 = *(const bf16x8*)(qg + l15 * HD + 32 + l4 * 8);

  float Lp[4] = {};
  float ep = 0.f;
  f32x4 oacc[4] = {};

  for (int mi = 0; mi < 32; ++mi) {
    const int m0 = mi * 32;
    // --- stage A: QK -> c = exp2(s*C1) -> wave-private LDS; accum L ---
    #pragma unroll
    for (int cf = 0; cf < 2; ++cf) {
      const u16* kr = kl + (size_t)(m0 + cf * 16) * HD;
      bf16x8 k0 = *(const bf16x8*)kr;
      bf16x8 k1 = *(const bf16x8*)(kr + 32);
      f32x4 s = {};
      s = __builtin_amdgcn_mfma_f32_16x16x32_bf16(qf0, k0, s, 0, 0, 0);
      s = __builtin_amdgcn_mfma_f32_16x16x32_bf16(qf1, k1, s, 0, 0, 0);
      #pragma unroll
      for (int r = 0; r < 4; ++r) {
        const float c = __builtin_amdgcn_exp2f(s[r] * C1);
        Lp[r] += c;
        cw[(l4 * 4 + r) * 40 + cf * 16 + l15] = f2b(c);   // [q][mloc]
      }
    }
    // --- transpose read (same wave -> lgkmcnt only) + a mult + pack ---
    bf16x8 c8 = *(const bf16x8*)(cw + l15 * 40 + l4 * 8); // q=l15, k=8 m's
    bf16x8 a8 = *(const bf16x8*)(ag + m0);                // same (q, m-slot)
    union PF { unsigned u[4]; bf16x8 v; } pf;
    #pragma unroll
    for (int j = 0; j < 4; ++j) {
      const float p0 = b2f((u16)c8[2 * j])     * b2f((u16)a8[2 * j]);
      const float p1 = b2f((u16)c8[2 * j + 1]) * b2f((u16)a8[2 * j + 1]);
      ep += p0 + p1;
      asm("v_cvt_pk_bf16_f32 %0, %1, %2" : "=v"(pf.u[j]) : "v"(p0), "v"(p1));
    }
    // --- PV: 4 d-tiles ---
    #pragma unroll
    for (int dt = 0; dt < 4; ++dt) {
      bf16x8 vf = *(const bf16x8*)(vl + (size_t)(dt * 16) * Nn + m0);
      oacc[dt] = __builtin_amdgcn_mfma_f32_16x16x32_bf16(pf.v, vf, oacc[dt], 0, 0, 0);
    }
  }

  // ---- reductions (wave-local) ----
  float linv[4];
  #pragma unroll
  for (int r = 0; r < 4; ++r) {
    float v = Lp[r];
    v += __shfl_xor(v, 1, 64); v += __shfl_xor(v, 2, 64);
    v += __shfl_xor(v, 4, 64); v += __shfl_xor(v, 8, 64);
    linv[r] = 1.0f / v;                       // L for q = l4*4+r
  }
  ep += __shfl_xor(ep, 16, 64);
  ep += __shfl_xor(ep, 32, 64);               // e1 for q = l15 (all lanes)

  // ---- epilogue: out = (SumV + linv*W1) / (1024 + linv*e1) ----
  float e1r[4];
  #pragma unroll
  for (int r = 0; r < 4; ++r) e1r[r] = __shfl(ep, l4 * 4 + r, 64);
  #pragma unroll
  for (int dt = 0; dt < 4; ++dt) {
    const int d = dt * 16 + l15;
    const float svd = sv[bh * HD + d];
    #pragma unroll
    for (int r = 0; r < 4; ++r) {
      const int q0 = l4 * 4 + r;
      const float E = fmaf(linv[r], e1r[r], 1024.0f);
      const float ov = fmaf(linv[r], oacc[dt][r], svd) / E;
      aoh[((size_t)b * Nn + qt * 16 + q0) * Cc + h * HD + d] = f2b(ov);
    }
  }
}

// ---------------- proj GEMM 64x128 + bias (r12 verbatim) --------------------
__global__ __launch_bounds__(256) void gemm_proj(
    const u16* __restrict__ Ah, const u16* __restrict__ Bh,
    const float* __restrict__ bias, float* __restrict__ dstf) {
  constexpr int K = 1024;
  __shared__ u16 As[64 * 32];
  __shared__ u16 Bs[128 * 32];
  const int tid = threadIdx.x;
  const int wave = tid >> 6, lane = tid & 63;
  const int l15 = lane & 15, l4 = lane >> 4;
  const int m0 = blockIdx.x * 64, n0 = blockIdx.y * 128;
  const int wr = wave >> 1, wc = wave & 1;
  const int srow = tid >> 2, scol = (tid & 3) * 8;
  f32x4 acc[2][4] = {};
  const u16* gA  = Ah + (size_t)(m0 + srow) * K + scol;
  const u16* gB0 = Bh + (size_t)(n0 + srow) * K + scol;
  const u16* gB1 = Bh + (size_t)(n0 + 64 + srow) * K + scol;
  for (int kt = 0; kt < K; kt += 32) {
    __syncthreads();
    __builtin_amdgcn_global_load_lds((gptr_t)(gA  + kt), (lptr_t)(As + wave * 512), 16, 0, 0);
    __builtin_amdgcn_global_load_lds((gptr_t)(gB0 + kt), (lptr_t)(Bs + wave * 512), 16, 0, 0);
    __builtin_amdgcn_global_load_lds((gptr_t)(gB1 + kt), (lptr_t)(Bs + 2048 + wave * 512), 16, 0, 0);
    __syncthreads();
    bf16x8 af[2], bf_[4];
    #pragma unroll
    for (int i = 0; i < 2; ++i)
      af[i] = *(const bf16x8*)(As + (wr * 32 + i * 16 + l15) * 32 + l4 * 8);
    #pragma unroll
    for (int i = 0; i < 4; ++i)
      bf_[i] = *(const bf16x8*)(Bs + (wc * 64 + i * 16 + l15) * 32 + l4 * 8);
    #pragma unroll
    for (int mi = 0; mi < 2; ++mi)
      #pragma unroll
      for (int ni = 0; ni < 4; ++ni)
        acc[mi][ni] = __builtin_amdgcn_mfma_f32_16x16x32_bf16(af[mi], bf_[ni], acc[mi][ni], 0, 0, 0);
  }
  #pragma unroll
  for (int mi = 0; mi < 2; ++mi)
    #pragma unroll
    for (int ni = 0; ni < 4; ++ni)
      #pragma unroll
      for (int r = 0; r < 4; ++r) {
        const int grow = m0 + wr * 32 + mi * 16 + l4 * 4 + r;
        const int gcol = n0 + wc * 64 + ni * 16 + l15;
        dstf[(size_t)grow * Cc + gcol] = acc[mi][ni][r] + bias[gcol];
      }
}

// ---------------------------------------------------------------------------
extern "C" void kernel_launch(void* const* d_in, const int* in_sizes, int n_in,
                              void* d_out, int out_size, void* d_ws, size_t ws_size,
                              hipStream_t stream) {
  (void)in_sizes; (void)n_in; (void)out_size; (void)ws_size;
  const float* x   = (const float*)d_in[0];
  const float* kin = (const float*)d_in[1];
  const float* af  = (const float*)d_in[2];
  const float* Wq  = (const float*)d_in[3];
  const float* Wkv = (const float*)d_in[4];
  const float* Wp  = (const float*)d_in[5];
  const float* bp  = (const float*)d_in[6];
  float* out = (float*)d_out;

  char* w = (char*)d_ws;
  auto take = [&](size_t bytes) { char* p = w; w += (bytes + 255) & ~(size_t)255; return p; };
  u16* WqT    = (u16*)take(2097152);
  u16* WkvTh  = (u16*)take(4194304);
  u16* WpTh   = (u16*)take(2097152);
  u16* xh     = (u16*)take(8388608);
  u16* kinh   = (u16*)take(8388608);
  u16* ab     = (u16*)take(8388608);
  u16* qb     = (u16*)take(8388608);
  u16* kb     = (u16*)take(8388608);
  u16* vtb    = (u16*)take(8388608);
  float* vtf  = (float*)take(16777216);
  float* sv   = (float*)take(16384);
  u16* aoh    = (u16*)take(8388608);

  prep_big<<<dim3(2048), dim3(256), 0, stream>>>(x, kin, af, xh, kinh, ab);
  prep_wt<<<dim3(1024), dim3(256), 0, stream>>>(Wq, Wkv, Wp, WqT, WkvTh, WpTh);

  gemm_qkv<<<dim3(64, 24), dim3(256), 0, stream>>>(xh, kinh, WqT, WkvTh, qb, kb, vtb, vtf);
  sumv_kernel<<<dim3(256), dim3(256), 0, stream>>>(vtf, sv);
  attn_kernel<<<dim3(1024), dim3(256), 0, stream>>>(qb, kb, vtb, sv, ab, aoh);
  gemm_proj<<<dim3(64, 8), dim3(256), 0, stream>>>(aoh, WpTh, bp, out);
}

// Round 18
// 226.289 us; speedup vs baseline: 1.0440x; 1.0440x over previous
//
#include <hip/hip_runtime.h>
#include <cmath>

// ---------------------------------------------------------------------------
// CrossAttention: B=4, N=1024, C=1024, H=16, HD=64
//   q = x@Wq ; kv = k_in@Wkv ; p = softmax(q k^T /8); z = p*a; w = softmax(z)
//   out = (w@v)@Wproj + b
// Numerics (r5/r9-proven): plain bf16 GEMMs; 2nd softmax linear at budget:
//   out = (SumV + linv*W1) / (1024 + linv*e1), c = exp(s/8), linv = 1/sum c.
// v18 = r17's barrier-free wave-private attn + the missing SOFTWARE PIPELINE:
// K/V/a for chunk mi+1 prefetched into regs during chunk mi (r17 loaded
// in-chunk -> serial latency chain, 140us). Also: vtf dropped, sumv reads
// bf16 vtb. Rest (preps, merged q+kv GEMM, proj) = r12 verbatim.
// ---------------------------------------------------------------------------

#define Bb 4
#define Nn 1024
#define Cc 1024
#define Hh 16
#define HD 64

typedef unsigned short u16;
typedef short bf16x8 __attribute__((ext_vector_type(8)));
typedef float f32x4 __attribute__((ext_vector_type(4)));
typedef unsigned short u16x4 __attribute__((ext_vector_type(4)));
typedef unsigned short u16x8 __attribute__((ext_vector_type(8)));
typedef __attribute__((address_space(1))) const void* gptr_t;
typedef __attribute__((address_space(3))) void* lptr_t;

__device__ __forceinline__ u16 f2b(float f) {
  union { float f; unsigned u; } x; x.f = f;
  unsigned u = x.u;
  return (u16)((u + 0x7FFFu + ((u >> 16) & 1u)) >> 16);
}
__device__ __forceinline__ float b2f(u16 h) {
  union { unsigned u; float f; } x; x.u = ((unsigned)h) << 16;
  return x.f;
}

// ---------------- prep: bf16 casts of x, k_in, attn_add (r12 verbatim) ------
__global__ __launch_bounds__(256) void prep_big(
    const float* __restrict__ x, const float* __restrict__ kin,
    const float* __restrict__ af,
    u16* __restrict__ xh, u16* __restrict__ kinh, u16* __restrict__ ab) {
  const int i = (blockIdx.x * 256 + threadIdx.x) * 8;   // 4M elems, grid 2048
  f32x4 x0 = *(const f32x4*)(x + i),   x1 = *(const f32x4*)(x + i + 4);
  f32x4 k0 = *(const f32x4*)(kin + i), k1 = *(const f32x4*)(kin + i + 4);
  f32x4 a0 = *(const f32x4*)(af + i),  a1 = *(const f32x4*)(af + i + 4);
  u16x8 xo, ko, ao;
  #pragma unroll
  for (int j = 0; j < 4; ++j) {
    xo[j] = f2b(x0[j]); xo[j + 4] = f2b(x1[j]);
    ko[j] = f2b(k0[j]); ko[j + 4] = f2b(k1[j]);
    ao[j] = f2b(a0[j]); ao[j + 4] = f2b(a1[j]);
  }
  *(u16x8*)(xh + i) = xo;
  *(u16x8*)(kinh + i) = ko;
  *(u16x8*)(ab + i) = ao;
}

// ---------------- tiled weight transposes (r12 verbatim) --------------------
__global__ __launch_bounds__(256) void prep_wt(
    const float* __restrict__ Wq, const float* __restrict__ Wkv,
    const float* __restrict__ Wp,
    u16* __restrict__ WqT, u16* __restrict__ WkvTh, u16* __restrict__ WpTh) {
  __shared__ float tile[64][65];
  int id = blockIdx.x;
  const float* src; int srcld; u16* dh; int ot0, it0;
  if (id < 256)      { src = Wq;  srcld = 1024; dh = WqT;
                       ot0 = (id >> 4) * 64; it0 = (id & 15) * 64; }
  else if (id < 768) { id -= 256; src = Wkv; srcld = 2048; dh = WkvTh;
                       ot0 = (id >> 4) * 64; it0 = (id & 15) * 64; }
  else               { id -= 768; src = Wp;  srcld = 1024; dh = WpTh;
                       ot0 = (id >> 4) * 64; it0 = (id & 15) * 64; }
  const int tr = threadIdx.x >> 4;
  const int tc = (threadIdx.x & 15) * 4;
  #pragma unroll
  for (int rr = 0; rr < 4; ++rr) {
    const int r = rr * 16 + tr;
    f32x4 v = *(const f32x4*)&src[(size_t)(it0 + r) * srcld + ot0 + tc];
    tile[r][tc] = v[0]; tile[r][tc + 1] = v[1];
    tile[r][tc + 2] = v[2]; tile[r][tc + 3] = v[3];
  }
  __syncthreads();
  #pragma unroll
  for (int rr = 0; rr < 4; ++rr) {
    const int o = rr * 16 + tr;
    u16x4 hv;
    #pragma unroll
    for (int j = 0; j < 4; ++j) hv[j] = f2b(tile[tc + j][o]);
    *(u16x4*)(dh + (size_t)(ot0 + o) * 1024 + it0 + tc) = hv;
  }
}

// ------- merged q+kv GEMM, 64x128 tile (r12 minus vtf writes) ---------------
__global__ __launch_bounds__(256) void gemm_qkv(
    const u16* __restrict__ xh, const u16* __restrict__ kinh,
    const u16* __restrict__ WqT, const u16* __restrict__ WkvTh,
    u16* __restrict__ qb, u16* __restrict__ kb, u16* __restrict__ vtb) {
  constexpr int K = 1024;
  __shared__ u16 As[64 * 32];
  __shared__ u16 Bs[128 * 32];
  const int tid = threadIdx.x;
  const int wave = tid >> 6, lane = tid & 63;
  const int l15 = lane & 15, l4 = lane >> 4;
  const int y = blockIdx.y;
  const bool isq = (y < 8);
  const u16* A  = isq ? xh : kinh;
  const u16* Bt = isq ? WqT : WkvTh;
  const int m0 = blockIdx.x * 64;
  const int n0 = (isq ? y : (y - 8)) * 128;
  const int wr = wave >> 1, wc = wave & 1;
  const int srow = tid >> 2, scol = (tid & 3) * 8;
  f32x4 acc[2][4] = {};
  const u16* gA  = A  + (size_t)(m0 + srow) * K + scol;
  const u16* gB0 = Bt + (size_t)(n0 + srow) * K + scol;
  const u16* gB1 = Bt + (size_t)(n0 + 64 + srow) * K + scol;
  for (int kt = 0; kt < K; kt += 32) {
    __syncthreads();
    __builtin_amdgcn_global_load_lds((gptr_t)(gA  + kt), (lptr_t)(As + wave * 512), 16, 0, 0);
    __builtin_amdgcn_global_load_lds((gptr_t)(gB0 + kt), (lptr_t)(Bs + wave * 512), 16, 0, 0);
    __builtin_amdgcn_global_load_lds((gptr_t)(gB1 + kt), (lptr_t)(Bs + 2048 + wave * 512), 16, 0, 0);
    __syncthreads();
    bf16x8 af[2], bf_[4];
    #pragma unroll
    for (int i = 0; i < 2; ++i)
      af[i] = *(const bf16x8*)(As + (wr * 32 + i * 16 + l15) * 32 + l4 * 8);
    #pragma unroll
    for (int i = 0; i < 4; ++i)
      bf_[i] = *(const bf16x8*)(Bs + (wc * 64 + i * 16 + l15) * 32 + l4 * 8);
    #pragma unroll
    for (int mi = 0; mi < 2; ++mi)
      #pragma unroll
      for (int ni = 0; ni < 4; ++ni)
        acc[mi][ni] = __builtin_amdgcn_mfma_f32_16x16x32_bf16(af[mi], bf_[ni], acc[mi][ni], 0, 0, 0);
  }
  #pragma unroll
  for (int mi = 0; mi < 2; ++mi)
    #pragma unroll
    for (int ni = 0; ni < 4; ++ni)
      #pragma unroll
      for (int r = 0; r < 4; ++r) {
        const int grow = m0 + wr * 32 + mi * 16 + l4 * 4 + r;   // b*N+n
        const int gcol = n0 + wc * 64 + ni * 16 + l15;
        const int bb = grow >> 10, n = grow & 1023;
        const float v = acc[mi][ni][r];
        if (isq) {
          const int hh = gcol >> 6, d = gcol & 63;
          qb[(((size_t)(bb * Hh + hh)) * Nn + n) * HD + d] = f2b(v);
        } else if (gcol < 1024) {   // k columns (block-uniform)
          const int hh = gcol >> 6, d = gcol & 63;
          kb[(((size_t)(bb * Hh + hh)) * Nn + n) * HD + d] = f2b(v);
        } else {                    // v columns
          const int cv = gcol - 1024;
          const int hh = cv >> 6, d = cv & 63;
          vtb[(((size_t)(bb * Hh + hh)) * HD + d) * Nn + n] = f2b(v);
        }
      }
}

// ---------------- SumV[b][h][d] = sum_m v[m][d] (bf16 vtb source) -----------
__global__ __launch_bounds__(256) void sumv_kernel(const u16* __restrict__ vtb,
                                                   float* __restrict__ sv) {
  const int bh = blockIdx.x >> 2, d16 = blockIdx.x & 3;
  const int t = threadIdx.x;
  const int d = d16 * 16 + (t >> 4), part = t & 15;
  const u16* src = vtb + ((size_t)bh * HD + d) * Nn + part * 64;
  float s = 0.f;
  #pragma unroll
  for (int i = 0; i < 64; i += 8) {
    bf16x8 v = *(const bf16x8*)(src + i);
    #pragma unroll
    for (int j = 0; j < 8; ++j) s += b2f((u16)v[j]);
  }
  s += __shfl_xor(s, 1, 64);
  s += __shfl_xor(s, 2, 64);
  s += __shfl_xor(s, 4, 64);
  s += __shfl_xor(s, 8, 64);
  if (part == 0) sv[(size_t)bh * HD + d] = s;
}

// ---------------- fused double-softmax attention (v18) ----------------------
// Barrier-free (r17) + register software-pipeline: K/V/a(mi+1) prefetched
// during chunk mi. Wave owns 16 q-rows; p-transpose via wave-private LDS
// (same-wave DS program order -> no __syncthreads). a multiplied after the
// transpose (contiguous 16B loads from linear ab).
__global__ __launch_bounds__(256, 3) void attn_kernel(
    const u16* __restrict__ qb, const u16* __restrict__ kb,
    const u16* __restrict__ vtb, const float* __restrict__ sv,
    const u16* __restrict__ ab, u16* __restrict__ aoh) {
  __shared__ u16 ct[4][16 * 40];            // per-wave c tile, 80B rows (5KB)

  const int tid = threadIdx.x;
  const int wave = tid >> 6, lane = tid & 63;
  const int l15 = lane & 15, l4 = lane >> 4;
  const int bid = (blockIdx.x & 7) * 128 + (blockIdx.x >> 3);   // XCD chunking
  const int unit = bid * 4 + wave;          // 4096 wave-units
  const int qt = unit & 63, h = (unit >> 6) & 15, b = unit >> 10;
  const size_t bh = (size_t)(b * Hh + h);
  const u16* qg = qb + (bh * Nn + qt * 16) * HD;
  const u16* kl = kb + bh * Nn * HD + (size_t)l15 * HD + l4 * 8;
  const u16* vl = vtb + bh * HD * Nn + (size_t)l15 * Nn + l4 * 8;
  const u16* ag = ab + ((size_t)(b * Nn + qt * 16 + l15)) * Nn + l4 * 8;
  u16* cw = ct[wave];
  constexpr float C1 = 0.125f * 1.44269504f;    // (1/8)*log2(e)

  // q fragments (16 q-rows, K=64)
  bf16x8 qf0 = *(const bf16x8*)(qg + l15 * HD + l4 * 8);
  bf16x8 qf1 = *(const bf16x8*)(qg + l15 * HD + 32 + l4 * 8);

  // prologue: chunk 0 into "cur" regs
  bf16x8 kc[4], vc[4], ac;
  kc[0] = *(const bf16x8*)kl;
  kc[1] = *(const bf16x8*)(kl + 32);
  kc[2] = *(const bf16x8*)(kl + 16 * HD);
  kc[3] = *(const bf16x8*)(kl + 16 * HD + 32);
  #pragma unroll
  for (int dt = 0; dt < 4; ++dt)
    vc[dt] = *(const bf16x8*)(vl + (size_t)(dt * 16) * Nn);
  ac = *(const bf16x8*)ag;

  float Lp[4] = {};
  float ep = 0.f;
  f32x4 oacc[4] = {};

  for (int mi = 0; mi < 32; ++mi) {
    const int m0 = mi * 32;
    // --- prefetch chunk mi+1 into "next" regs ---
    bf16x8 kn[4], vn[4], an;
    if (mi < 31) {
      const u16* kr = kl + (size_t)(m0 + 32) * HD;
      kn[0] = *(const bf16x8*)kr;
      kn[1] = *(const bf16x8*)(kr + 32);
      kn[2] = *(const bf16x8*)(kr + 16 * HD);
      kn[3] = *(const bf16x8*)(kr + 16 * HD + 32);
      #pragma unroll
      for (int dt = 0; dt < 4; ++dt)
        vn[dt] = *(const bf16x8*)(vl + (size_t)(dt * 16) * Nn + m0 + 32);
      an = *(const bf16x8*)(ag + m0 + 32);
    }
    // --- stage A: QK -> c = exp2(s*C1) -> wave-private LDS; accum L ---
    #pragma unroll
    for (int cf = 0; cf < 2; ++cf) {
      f32x4 s = {};
      s = __builtin_amdgcn_mfma_f32_16x16x32_bf16(qf0, kc[cf * 2], s, 0, 0, 0);
      s = __builtin_amdgcn_mfma_f32_16x16x32_bf16(qf1, kc[cf * 2 + 1], s, 0, 0, 0);
      #pragma unroll
      for (int r = 0; r < 4; ++r) {
        const float c = __builtin_amdgcn_exp2f(s[r] * C1);
        Lp[r] += c;
        cw[(l4 * 4 + r) * 40 + cf * 16 + l15] = f2b(c);   // [q][mloc]
      }
    }
    // --- transpose read (same-wave DS order) + a mult + pack ---
    bf16x8 c8 = *(const bf16x8*)(cw + l15 * 40 + l4 * 8); // q=l15, 8 m's
    union PF { unsigned u[4]; bf16x8 v; } pf;
    #pragma unroll
    for (int j = 0; j < 4; ++j) {
      const float p0 = b2f((u16)c8[2 * j])     * b2f((u16)ac[2 * j]);
      const float p1 = b2f((u16)c8[2 * j + 1]) * b2f((u16)ac[2 * j + 1]);
      ep += p0 + p1;
      asm("v_cvt_pk_bf16_f32 %0, %1, %2" : "=v"(pf.u[j]) : "v"(p0), "v"(p1));
    }
    // --- PV: 4 d-tiles ---
    #pragma unroll
    for (int dt = 0; dt < 4; ++dt)
      oacc[dt] = __builtin_amdgcn_mfma_f32_16x16x32_bf16(pf.v, vc[dt], oacc[dt], 0, 0, 0);
    // --- swap ---
    #pragma unroll
    for (int j = 0; j < 4; ++j) { kc[j] = kn[j]; vc[j] = vn[j]; }
    ac = an;
  }

  // ---- reductions (wave-local) ----
  float linv[4];
  #pragma unroll
  for (int r = 0; r < 4; ++r) {
    float v = Lp[r];
    v += __shfl_xor(v, 1, 64); v += __shfl_xor(v, 2, 64);
    v += __shfl_xor(v, 4, 64); v += __shfl_xor(v, 8, 64);
    linv[r] = 1.0f / v;                       // 1/L for q = l4*4+r
  }
  ep += __shfl_xor(ep, 16, 64);
  ep += __shfl_xor(ep, 32, 64);               // e1 for q = l15 (all lanes)

  // ---- epilogue: out = (SumV + linv*W1) / (1024 + linv*e1) ----
  float e1r[4];
  #pragma unroll
  for (int r = 0; r < 4; ++r) e1r[r] = __shfl(ep, l4 * 4 + r, 64);
  #pragma unroll
  for (int dt = 0; dt < 4; ++dt) {
    const int d = dt * 16 + l15;
    const float svd = sv[bh * HD + d];
    #pragma unroll
    for (int r = 0; r < 4; ++r) {
      const int q0 = l4 * 4 + r;
      const float E = fmaf(linv[r], e1r[r], 1024.0f);
      const float ov = fmaf(linv[r], oacc[dt][r], svd) / E;
      aoh[((size_t)b * Nn + qt * 16 + q0) * Cc + h * HD + d] = f2b(ov);
    }
  }
}

// ---------------- proj GEMM 64x128 + bias (r12 verbatim) --------------------
__global__ __launch_bounds__(256) void gemm_proj(
    const u16* __restrict__ Ah, const u16* __restrict__ Bh,
    const float* __restrict__ bias, float* __restrict__ dstf) {
  constexpr int K = 1024;
  __shared__ u16 As[64 * 32];
  __shared__ u16 Bs[128 * 32];
  const int tid = threadIdx.x;
  const int wave = tid >> 6, lane = tid & 63;
  const int l15 = lane & 15, l4 = lane >> 4;
  const int m0 = blockIdx.x * 64, n0 = blockIdx.y * 128;
  const int wr = wave >> 1, wc = wave & 1;
  const int srow = tid >> 2, scol = (tid & 3) * 8;
  f32x4 acc[2][4] = {};
  const u16* gA  = Ah + (size_t)(m0 + srow) * K + scol;
  const u16* gB0 = Bh + (size_t)(n0 + srow) * K + scol;
  const u16* gB1 = Bh + (size_t)(n0 + 64 + srow) * K + scol;
  for (int kt = 0; kt < K; kt += 32) {
    __syncthreads();
    __builtin_amdgcn_global_load_lds((gptr_t)(gA  + kt), (lptr_t)(As + wave * 512), 16, 0, 0);
    __builtin_amdgcn_global_load_lds((gptr_t)(gB0 + kt), (lptr_t)(Bs + wave * 512), 16, 0, 0);
    __builtin_amdgcn_global_load_lds((gptr_t)(gB1 + kt), (lptr_t)(Bs + 2048 + wave * 512), 16, 0, 0);
    __syncthreads();
    bf16x8 af[2], bf_[4];
    #pragma unroll
    for (int i = 0; i < 2; ++i)
      af[i] = *(const bf16x8*)(As + (wr * 32 + i * 16 + l15) * 32 + l4 * 8);
    #pragma unroll
    for (int i = 0; i < 4; ++i)
      bf_[i] = *(const bf16x8*)(Bs + (wc * 64 + i * 16 + l15) * 32 + l4 * 8);
    #pragma unroll
    for (int mi = 0; mi < 2; ++mi)
      #pragma unroll
      for (int ni = 0; ni < 4; ++ni)
        acc[mi][ni] = __builtin_amdgcn_mfma_f32_16x16x32_bf16(af[mi], bf_[ni], acc[mi][ni], 0, 0, 0);
  }
  #pragma unroll
  for (int mi = 0; mi < 2; ++mi)
    #pragma unroll
    for (int ni = 0; ni < 4; ++ni)
      #pragma unroll
      for (int r = 0; r < 4; ++r) {
        const int grow = m0 + wr * 32 + mi * 16 + l4 * 4 + r;
        const int gcol = n0 + wc * 64 + ni * 16 + l15;
        dstf[(size_t)grow * Cc + gcol] = acc[mi][ni][r] + bias[gcol];
      }
}

// ---------------------------------------------------------------------------
extern "C" void kernel_launch(void* const* d_in, const int* in_sizes, int n_in,
                              void* d_out, int out_size, void* d_ws, size_t ws_size,
                              hipStream_t stream) {
  (void)in_sizes; (void)n_in; (void)out_size; (void)ws_size;
  const float* x   = (const float*)d_in[0];
  const float* kin = (const float*)d_in[1];
  const float* af  = (const float*)d_in[2];
  const float* Wq  = (const float*)d_in[3];
  const float* Wkv = (const float*)d_in[4];
  const float* Wp  = (const float*)d_in[5];
  const float* bp  = (const float*)d_in[6];
  float* out = (float*)d_out;

  char* w = (char*)d_ws;
  auto take = [&](size_t bytes) { char* p = w; w += (bytes + 255) & ~(size_t)255; return p; };
  u16* WqT    = (u16*)take(2097152);
  u16* WkvTh  = (u16*)take(4194304);
  u16* WpTh   = (u16*)take(2097152);
  u16* xh     = (u16*)take(8388608);
  u16* kinh   = (u16*)take(8388608);
  u16* ab     = (u16*)take(8388608);
  u16* qb     = (u16*)take(8388608);
  u16* kb     = (u16*)take(8388608);
  u16* vtb    = (u16*)take(8388608);
  float* sv   = (float*)take(16384);
  u16* aoh    = (u16*)take(8388608);

  prep_big<<<dim3(2048), dim3(256), 0, stream>>>(x, kin, af, xh, kinh, ab);
  prep_wt<<<dim3(1024), dim3(256), 0, stream>>>(Wq, Wkv, Wp, WqT, WkvTh, WpTh);

  gemm_qkv<<<dim3(64, 24), dim3(256), 0, stream>>>(xh, kinh, WqT, WkvTh, qb, kb, vtb);
  sumv_kernel<<<dim3(256), dim3(256), 0, stream>>>(vtb, sv);
  attn_kernel<<<dim3(1024), dim3(256), 0, stream>>>(qb, kb, vtb, sv, ab, aoh);
  gemm_proj<<<dim3(64, 8), dim3(256), 0, stream>>>(aoh, WpTh, bp, out);
}